// Round 5
// baseline (1712.338 us; speedup 1.0000x reference)
//
#include <hip/hip_runtime.h>
#include <hip/hip_cooperative_groups.h>

#define K_DIM 2048
#define N_DIM 2048
#define M_DIM 16384

typedef int v4i __attribute__((ext_vector_type(4)));
typedef int v16i __attribute__((ext_vector_type(16)));

// ---------------- ws layout ----------------
// [0]      double part[512]      (4 KB)
// [8192]   float  invsw
// [12288]  float  si[16384]      (64 KB)
// [77824]  int8   qw_t           (4 MiB)  tiled [bn(8)][ks(32)][k16(4)][row(256)][16B]
// [+4MiB]  int8   qx_t           (32 MiB) tiled [bm(64)][ks(32)][k16(4)][row(256)][16B]

__device__ __forceinline__ void lds16(const void* g, void* l) {
    __builtin_amdgcn_global_load_lds(
        (const __attribute__((address_space(1))) unsigned int*)g,
        (__attribute__((address_space(3))) unsigned int*)l,
        16, 0, 0);
}

// ---------- fused prep: |W|-sum + quant_x + (grid.sync) + quant_w ----------
// Cooperative, 512 blocks x 256 threads (co-resident: ~8.3 KB LDS, low VGPR).
__global__ __launch_bounds__(256) void k_prep(const float* __restrict__ x,
                                              const float* __restrict__ w,
                                              signed char* __restrict__ qx_t,
                                              signed char* __restrict__ qw_t,
                                              double* __restrict__ part,
                                              float* __restrict__ si_out,
                                              float* __restrict__ invsw_out) {
    __shared__ int lbuf[2048];  // [chunk(128)=ks*4+k16][row4(4)][b(4)]
    __shared__ double sp[4];
    __shared__ float s_invsw;
    const int t = threadIdx.x, b = blockIdx.x;
    const int lane = t & 63, wv = t >> 6;

    // --- Phase A: |W| partial sum for this block's 1/512 stripe (8 float4/thread) ---
    {
        const float4* w4 = (const float4*)w;
        double s = 0.0;
#pragma unroll
        for (int i = 0; i < 8; i++) {
            float4 v = w4[(size_t)b * 2048 + i * 256 + t];
            s += (double)fabsf(v.x) + (double)fabsf(v.y) +
                 (double)fabsf(v.z) + (double)fabsf(v.w);
        }
#pragma unroll
        for (int off = 32; off; off >>= 1) s += __shfl_xor(s, off, 64);
        if (lane == 0) sp[wv] = s;
        __syncthreads();
        if (t == 0) part[b] = sp[0] + sp[1] + sp[2] + sp[3];
        __syncthreads();
    }

    // --- Phase B: quant_x, 32 rows per block (8 groups of 4, one row/wave) ---
    for (int g = 0; g < 8; g++) {
        int rows0 = b * 32 + g * 4;
        int row = rows0 + wv;
        const float4* xr = (const float4*)(x + (size_t)row * K_DIM);
        float4 v[8];
        float mx = 0.f;
#pragma unroll
        for (int c = 0; c < 8; c++) {
            v[c] = xr[c * 64 + lane];
            mx = fmaxf(mx, fmaxf(fmaxf(fabsf(v[c].x), fabsf(v[c].y)),
                                 fmaxf(fabsf(v[c].z), fabsf(v[c].w))));
        }
#pragma unroll
        for (int off = 32; off; off >>= 1) mx = fmaxf(mx, __shfl_xor(mx, off, 64));
        float si = 127.0f / fmaxf(mx, 1e-5f);  // bit-exact vs reference
        if (lane == 0) si_out[row] = si;

        int k16 = (lane >> 2) & 3, bb = lane & 3, ksBase = lane >> 4;
#pragma unroll
        for (int c = 0; c < 8; c++) {
            int q0 = (int)fminf(fmaxf(rintf(v[c].x * si), -128.f), 127.f);
            int q1 = (int)fminf(fmaxf(rintf(v[c].y * si), -128.f), 127.f);
            int q2 = (int)fminf(fmaxf(rintf(v[c].z * si), -128.f), 127.f);
            int q3 = (int)fminf(fmaxf(rintf(v[c].w * si), -128.f), 127.f);
            int q = (q0 & 255) | ((q1 & 255) << 8) | ((q2 & 255) << 16) | ((q3 & 255) << 24);
            int ks = 4 * c + ksBase;
            lbuf[(ks * 4 + k16) * 16 + wv * 4 + bb] = q;
        }
        __syncthreads();
        int bm = rows0 >> 8, ri0 = rows0 & 255;
        int* qdst = (int*)(qx_t + (size_t)bm * 524288 + (size_t)ri0 * 16);
#pragma unroll
        for (int r = 0; r < 8; r++) {
            int chunk = r * 16 + (t >> 4);
            int i16 = t & 15;
            int ks = chunk >> 2, kk = chunk & 3;
            int row4 = i16 >> 2, b4 = i16 & 3;
            qdst[ks * 4096 + kk * 1024 + row4 * 4 + b4] = lbuf[chunk * 16 + i16];
        }
        __syncthreads();
    }

    cooperative_groups::this_grid().sync();

    // --- Phase C: reduce part[512] (deterministic, identical in every block) + quant_w ---
    // qw_t layout now mirrors qx_t: [bn(8)][ks(32)][k16(4)][row(256)][16B]
    {
        double s = part[t] + part[t + 256];
#pragma unroll
        for (int off = 32; off; off >>= 1) s += __shfl_xor(s, off, 64);
        if (lane == 0) sp[wv] = s;
        __syncthreads();
        if (t == 0) {
            double total = sp[0] + sp[1] + sp[2] + sp[3];
            float mean = (float)(total * (1.0 / (double)(N_DIM * K_DIM)));
            s_invsw = fmaxf(mean, 1e-5f);
            if (b == 0) *invsw_out = s_invsw;
        }
        __syncthreads();
        float sw = 1.0f / s_invsw;  // reference's sw

        int rows0 = b * 4;
        int row = rows0 + wv;  // 0..2047
        const float4* wr_ = (const float4*)(w + (size_t)row * K_DIM);
        int k16 = (lane >> 2) & 3, bb = lane & 3, ksBase = lane >> 4;
#pragma unroll
        for (int c = 0; c < 8; c++) {
            float4 v = wr_[c * 64 + lane];
            int q0 = (int)fminf(fmaxf(rintf(v.x * sw), -1.f), 1.f);
            int q1 = (int)fminf(fmaxf(rintf(v.y * sw), -1.f), 1.f);
            int q2 = (int)fminf(fmaxf(rintf(v.z * sw), -1.f), 1.f);
            int q3 = (int)fminf(fmaxf(rintf(v.w * sw), -1.f), 1.f);
            int q = (q0 & 255) | ((q1 & 255) << 8) | ((q2 & 255) << 16) | ((q3 & 255) << 24);
            int ks = 4 * c + ksBase;
            lbuf[(ks * 4 + k16) * 16 + wv * 4 + bb] = q;
        }
        __syncthreads();
        int bn = rows0 >> 8, ri0 = rows0 & 255;
        int* qdst = (int*)(qw_t + (size_t)bn * 524288 + (size_t)ri0 * 16);
#pragma unroll
        for (int r = 0; r < 8; r++) {
            int chunk = r * 16 + (t >> 4);
            int i16 = t & 15;
            int ks = chunk >> 2, kk = chunk & 3;
            int row4 = i16 >> 2, b4 = i16 & 3;
            qdst[ks * 4096 + kk * 1024 + row4 * 4 + b4] = lbuf[chunk * 16 + i16];
        }
    }
}

// ---------- int8 GEMM, 256x256 block tile, 128x128 wave tile, 32x32x32 MFMA ----------
// ROUND 4 CHANGE (arithmetic-intensity fix — r3 counters showed the structure at
// the LDS/MFMA balance point, 90 B/cyc effective = the wall):
//   * 256x256 block tile, 4 waves of 128x128 (acc[4][4], 256 AGPRs).
//     Fragment reads per block-K-step: 48 KB -> 64 KB but for 2x the ops:
//     0.0176 -> 0.0114 LDS-B/op, now MFMA-bound (per-CU 82 B/cyc < 90 ceiling).
//   * As[2]+Bs[2] = 64 KB -> 2 blocks/CU guaranteed; 512 blocks = one pass.
//   * Stage(ks+1) issued EARLY in iter ks (right after barrier): the DMA gets
//     the full ~2300-cyc compute phase to land, so the vmcnt(0) at the next
//     iter top is ~free. Single barrier per K-step (readers provably done).
__global__ __launch_bounds__(256, 2) void k_gemm(const signed char* __restrict__ qx_t,
                                                 const signed char* __restrict__ qw_t,
                                                 const float* __restrict__ si,
                                                 const float* __restrict__ invsw_p,
                                                 float* __restrict__ out) {
    __shared__ __align__(16) signed char As[2][16384];  // [k16(4)][row(256)][16B]
    __shared__ __align__(16) signed char Bs[2][16384];  // [k16(4)][row(256)][16B]
    const int t = threadIdx.x;
    const int lane = t & 63, wv = t >> 6;
    const int wr = wv >> 1, wc = wv & 1;   // 2x2 wave grid; wave tile 128x128
    const int l31 = lane & 31, lh = lane >> 5;

    // T1: bijective chunked XCD swizzle (nwg=512, 8 XCDs, 64 blocks/XCD)
    const int wg = blockIdx.x;
    const int swz = (wg & 7) * 64 + (wg >> 3);
    const int bn = swz & 7, bm = swz >> 3;  // bn inner: XCD k owns bm in [8k, 8k+8)

    const signed char* aT = qx_t + (size_t)bm * 524288;
    const signed char* bT = qw_t + (size_t)bn * 524288;
    const int t16 = t << 4;

#define STAGE(buf, ksv)                                      \
    {                                                        \
        const signed char* aS = aT + ((size_t)(ksv) << 14);  \
        const signed char* bS = bT + ((size_t)(ksv) << 14);  \
        signed char* Ad = As[buf];                           \
        signed char* Bd = Bs[buf];                           \
        lds16(aS + t16,         Ad + t16);                   \
        lds16(aS + 4096 + t16,  Ad + 4096 + t16);            \
        lds16(aS + 8192 + t16,  Ad + 8192 + t16);            \
        lds16(aS + 12288 + t16, Ad + 12288 + t16);           \
        lds16(bS + t16,         Bd + t16);                   \
        lds16(bS + 4096 + t16,  Bd + 4096 + t16);            \
        lds16(bS + 8192 + t16,  Bd + 8192 + t16);            \
        lds16(bS + 12288 + t16, Bd + 12288 + t16);           \
    }

    v16i acc[4][4] = {};

    // per-iter: vmcnt(0) retires {A(ks),B(ks)} (issued one full compute phase
    // ago); single barrier; stage (ks+1) immediately; then 2 k-halves of
    // {8 ds_read_b128, 16 MFMA} with setprio around the MFMA cluster.
#define ITER(ksv, buf)                                                                                 \
    {                                                                                                  \
        asm volatile("s_waitcnt vmcnt(0)" ::: "memory");                                               \
        __builtin_amdgcn_s_barrier();                                                                  \
        __builtin_amdgcn_sched_barrier(0);                                                             \
        if ((ksv) < 31) STAGE((buf) ^ 1, (ksv) + 1);                                                   \
        _Pragma("unroll")                                                                              \
        for (int h = 0; h < 2; h++) {                                                                  \
            v4i af[4], bf[4];                                                                          \
            _Pragma("unroll")                                                                          \
            for (int mt = 0; mt < 4; mt++)                                                             \
                af[mt] = *(const v4i*)(As[buf] + (((h * 2 + lh) * 256 + wr * 128 + mt * 32 + l31) << 4)); \
            _Pragma("unroll")                                                                          \
            for (int nt = 0; nt < 4; nt++)                                                             \
                bf[nt] = *(const v4i*)(Bs[buf] + (((h * 2 + lh) * 256 + wc * 128 + nt * 32 + l31) << 4)); \
            __builtin_amdgcn_s_setprio(1);                                                             \
            _Pragma("unroll")                                                                          \
            for (int mt = 0; mt < 4; mt++)                                                             \
                _Pragma("unroll")                                                                      \
                for (int nt = 0; nt < 4; nt++)                                                         \
                    acc[mt][nt] = __builtin_amdgcn_mfma_i32_32x32x32_i8(af[mt], bf[nt], acc[mt][nt], 0, 0, 0); \
            __builtin_amdgcn_s_setprio(0);                                                             \
        }                                                                                              \
    }

    STAGE(0, 0);
    for (int ks = 0; ks < 32; ks += 2) {
        ITER(ks, 0);
        ITER(ks + 1, 1);
    }

#undef ITER
#undef STAGE

    // epilogue: C/D 32x32 layout col=lane&31, row=(r&3)+8*(r>>2)+4*(lane>>5)
    float invsw = *invsw_p;
#pragma unroll
    for (int mt = 0; mt < 4; mt++) {
        int rowb = bm * 256 + wr * 128 + mt * 32 + (lh << 2);
        float sc[16];
#pragma unroll
        for (int r = 0; r < 16; r++)
            sc[r] = invsw / si[rowb + (r & 3) + ((r >> 2) << 3)];
#pragma unroll
        for (int nt = 0; nt < 4; nt++) {
            int col = bn * 256 + wc * 128 + nt * 32 + l31;
#pragma unroll
            for (int r = 0; r < 16; r++) {
                int row = rowb + (r & 3) + ((r >> 2) << 3);
                float vv = (float)acc[mt][nt][r] * sc[r];
                out[(size_t)row * N_DIM + col] = (float)(_Float16)vv;
            }
        }
    }
}

extern "C" void kernel_launch(void* const* d_in, const int* in_sizes, int n_in,
                              void* d_out, int out_size, void* d_ws, size_t ws_size,
                              hipStream_t stream) {
    const float* x = (const float*)d_in[0];
    const float* w = (const float*)d_in[1];
    float* out = (float*)d_out;
    char* ws = (char*)d_ws;

    double* part = (double*)ws;
    float* invsw = (float*)(ws + 8192);
    float* si = (float*)(ws + 12288);
    signed char* qw_t = (signed char*)(ws + 12288 + 65536);
    signed char* qx_t = qw_t + (size_t)N_DIM * K_DIM;

    void* args[] = {(void*)&x, (void*)&w, (void*)&qx_t, (void*)&qw_t,
                    (void*)&part, (void*)&si, (void*)&invsw};
    hipLaunchCooperativeKernel((void*)k_prep, dim3(512), dim3(256), args, 0, stream);
    k_gemm<<<512, 256, 0, stream>>>(qx_t, qw_t, si, invsw, out);
}

// Round 6
// 379.545 us; speedup vs baseline: 4.5116x; 4.5116x over previous
//
#include <hip/hip_runtime.h>
#include <hip/hip_cooperative_groups.h>

#define K_DIM 2048
#define N_DIM 2048
#define M_DIM 16384

typedef int v4i __attribute__((ext_vector_type(4)));
typedef int v16i __attribute__((ext_vector_type(16)));

// ---------------- ws layout ----------------
// [0]      double part[512]      (4 KB)
// [8192]   float  invsw
// [12288]  float  si[16384]      (64 KB)
// [77824]  int8   qw_t           (4 MiB)  tiled [bn(8)][ks(32)][k16(4)][row(256)][16B]
// [+4MiB]  int8   qx_t           (32 MiB) tiled [bm(64)][ks(32)][k16(4)][row(256)][16B]

__device__ __forceinline__ void lds16(const void* g, void* l) {
    __builtin_amdgcn_global_load_lds(
        (const __attribute__((address_space(1))) unsigned int*)g,
        (__attribute__((address_space(3))) unsigned int*)l,
        16, 0, 0);
}

// ---------- fused prep: |W|-sum + quant_x + (grid.sync) + quant_w ----------
// Cooperative, 512 blocks x 256 threads (co-resident: ~8.3 KB LDS, low VGPR).
// UNCHANGED from round 5 (verified: passed with absmax 0.05566406).
__global__ __launch_bounds__(256) void k_prep(const float* __restrict__ x,
                                              const float* __restrict__ w,
                                              signed char* __restrict__ qx_t,
                                              signed char* __restrict__ qw_t,
                                              double* __restrict__ part,
                                              float* __restrict__ si_out,
                                              float* __restrict__ invsw_out) {
    __shared__ int lbuf[2048];  // [chunk(128)=ks*4+k16][row4(4)][b(4)]
    __shared__ double sp[4];
    __shared__ float s_invsw;
    const int t = threadIdx.x, b = blockIdx.x;
    const int lane = t & 63, wv = t >> 6;

    // --- Phase A: |W| partial sum for this block's 1/512 stripe (8 float4/thread) ---
    {
        const float4* w4 = (const float4*)w;
        double s = 0.0;
#pragma unroll
        for (int i = 0; i < 8; i++) {
            float4 v = w4[(size_t)b * 2048 + i * 256 + t];
            s += (double)fabsf(v.x) + (double)fabsf(v.y) +
                 (double)fabsf(v.z) + (double)fabsf(v.w);
        }
#pragma unroll
        for (int off = 32; off; off >>= 1) s += __shfl_xor(s, off, 64);
        if (lane == 0) sp[wv] = s;
        __syncthreads();
        if (t == 0) part[b] = sp[0] + sp[1] + sp[2] + sp[3];
        __syncthreads();
    }

    // --- Phase B: quant_x, 32 rows per block (8 groups of 4, one row/wave) ---
    for (int g = 0; g < 8; g++) {
        int rows0 = b * 32 + g * 4;
        int row = rows0 + wv;
        const float4* xr = (const float4*)(x + (size_t)row * K_DIM);
        float4 v[8];
        float mx = 0.f;
#pragma unroll
        for (int c = 0; c < 8; c++) {
            v[c] = xr[c * 64 + lane];
            mx = fmaxf(mx, fmaxf(fmaxf(fabsf(v[c].x), fabsf(v[c].y)),
                                 fmaxf(fabsf(v[c].z), fabsf(v[c].w))));
        }
#pragma unroll
        for (int off = 32; off; off >>= 1) mx = fmaxf(mx, __shfl_xor(mx, off, 64));
        float si = 127.0f / fmaxf(mx, 1e-5f);  // bit-exact vs reference
        if (lane == 0) si_out[row] = si;

        int k16 = (lane >> 2) & 3, bb = lane & 3, ksBase = lane >> 4;
#pragma unroll
        for (int c = 0; c < 8; c++) {
            int q0 = (int)fminf(fmaxf(rintf(v[c].x * si), -128.f), 127.f);
            int q1 = (int)fminf(fmaxf(rintf(v[c].y * si), -128.f), 127.f);
            int q2 = (int)fminf(fmaxf(rintf(v[c].z * si), -128.f), 127.f);
            int q3 = (int)fminf(fmaxf(rintf(v[c].w * si), -128.f), 127.f);
            int q = (q0 & 255) | ((q1 & 255) << 8) | ((q2 & 255) << 16) | ((q3 & 255) << 24);
            int ks = 4 * c + ksBase;
            lbuf[(ks * 4 + k16) * 16 + wv * 4 + bb] = q;
        }
        __syncthreads();
        int bm = rows0 >> 8, ri0 = rows0 & 255;
        int* qdst = (int*)(qx_t + (size_t)bm * 524288 + (size_t)ri0 * 16);
#pragma unroll
        for (int r = 0; r < 8; r++) {
            int chunk = r * 16 + (t >> 4);
            int i16 = t & 15;
            int ks = chunk >> 2, kk = chunk & 3;
            int row4 = i16 >> 2, b4 = i16 & 3;
            qdst[ks * 4096 + kk * 1024 + row4 * 4 + b4] = lbuf[chunk * 16 + i16];
        }
        __syncthreads();
    }

    cooperative_groups::this_grid().sync();

    // --- Phase C: reduce part[512] (deterministic, identical in every block) + quant_w ---
    {
        double s = part[t] + part[t + 256];
#pragma unroll
        for (int off = 32; off; off >>= 1) s += __shfl_xor(s, off, 64);
        if (lane == 0) sp[wv] = s;
        __syncthreads();
        if (t == 0) {
            double total = sp[0] + sp[1] + sp[2] + sp[3];
            float mean = (float)(total * (1.0 / (double)(N_DIM * K_DIM)));
            s_invsw = fmaxf(mean, 1e-5f);
            if (b == 0) *invsw_out = s_invsw;
        }
        __syncthreads();
        float sw = 1.0f / s_invsw;  // reference's sw

        int rows0 = b * 4;
        int row = rows0 + wv;  // 0..2047
        const float4* wr_ = (const float4*)(w + (size_t)row * K_DIM);
        int k16 = (lane >> 2) & 3, bb = lane & 3, ksBase = lane >> 4;
#pragma unroll
        for (int c = 0; c < 8; c++) {
            float4 v = wr_[c * 64 + lane];
            int q0 = (int)fminf(fmaxf(rintf(v.x * sw), -1.f), 1.f);
            int q1 = (int)fminf(fmaxf(rintf(v.y * sw), -1.f), 1.f);
            int q2 = (int)fminf(fmaxf(rintf(v.z * sw), -1.f), 1.f);
            int q3 = (int)fminf(fmaxf(rintf(v.w * sw), -1.f), 1.f);
            int q = (q0 & 255) | ((q1 & 255) << 8) | ((q2 & 255) << 16) | ((q3 & 255) << 24);
            int ks = 4 * c + ksBase;
            lbuf[(ks * 4 + k16) * 16 + wv * 4 + bb] = q;
        }
        __syncthreads();
        int bn = rows0 >> 8, ri0 = rows0 & 255;
        int* qdst = (int*)(qw_t + (size_t)bn * 524288 + (size_t)ri0 * 16);
#pragma unroll
        for (int r = 0; r < 8; r++) {
            int chunk = r * 16 + (t >> 4);
            int i16 = t & 15;
            int ks = chunk >> 2, kk = chunk & 3;
            int row4 = i16 >> 2, b4 = i16 & 3;
            qdst[ks * 4096 + kk * 1024 + row4 * 4 + b4] = lbuf[chunk * 16 + i16];
        }
    }
}

// ---------- int8 GEMM, 256x256 block tile, 128x128 wave tile, 32x32x32 MFMA ----------
// ROUND 5 CHANGE (fix the r5 SPILL — counters showed 7.5 GB scratch traffic):
//   * __launch_bounds__(256, 1): 1 wave/SIMD -> up to ~450 regs/thread without
//     spill (m08). acc[4][4]=256 AGPR + 64 frag VGPR + ~30 addr = ~350. The
//     r5 attempt had the right tile math but a 256-reg budget -> spilled.
//   * LDS-read traffic at 128x128 wave tiles: 96 KB/CU/K-step = 82 B/cyc at
//     the 1170-cyc MFMA floor -> MFMA-bound (r3's 128x64 waves were pinned at
//     the 90 B/cyc LDS wall; that is the measured 85 us ceiling).
//   * 1 block/CU -> no cross-block TLP, so: triple-buffered 96 KB LDS with
//     depth-2 prefetch (counted vmcnt(8), ~2400 cyc for staging to land) and
//     16 independent ds_reads hoisted ahead of 32 independent MFMAs.
//   * No setprio (1 wave/SIMD: nothing to arbitrate).
__global__ __launch_bounds__(256, 1) void k_gemm(const signed char* __restrict__ qx_t,
                                                 const signed char* __restrict__ qw_t,
                                                 const float* __restrict__ si,
                                                 const float* __restrict__ invsw_p,
                                                 float* __restrict__ out) {
    __shared__ __align__(16) signed char As[3][16384];  // [k16(4)][row(256)][16B]
    __shared__ __align__(16) signed char Bs[3][16384];  // [k16(4)][row(256)][16B]
    const int t = threadIdx.x;
    const int lane = t & 63, wv = t >> 6;
    const int wr = wv >> 1, wc = wv & 1;   // 2x2 wave grid; wave tile 128x128
    const int l31 = lane & 31, lh = lane >> 5;

    // T1: bijective chunked XCD swizzle (nwg=512, 8 XCDs, 64 blocks/XCD)
    const int wg = blockIdx.x;
    const int swz = (wg & 7) * 64 + (wg >> 3);
    const int bn = swz & 7, bm = swz >> 3;  // bn inner: XCD k owns bm in [8k, 8k+8)

    const signed char* aT = qx_t + (size_t)bm * 524288;
    const signed char* bT = qw_t + (size_t)bn * 524288;
    const int t16 = t << 4;

#define STAGE(buf, ksv)                                      \
    {                                                        \
        const signed char* aS = aT + ((size_t)(ksv) << 14);  \
        const signed char* bS = bT + ((size_t)(ksv) << 14);  \
        signed char* Ad = As[buf];                           \
        signed char* Bd = Bs[buf];                           \
        lds16(aS + t16,         Ad + t16);                   \
        lds16(aS + 4096 + t16,  Ad + 4096 + t16);            \
        lds16(aS + 8192 + t16,  Ad + 8192 + t16);            \
        lds16(aS + 12288 + t16, Ad + 12288 + t16);           \
        lds16(bS + t16,         Bd + t16);                   \
        lds16(bS + 4096 + t16,  Bd + 4096 + t16);            \
        lds16(bS + 8192 + t16,  Bd + 8192 + t16);            \
        lds16(bS + 12288 + t16, Bd + 12288 + t16);           \
    }

    v16i acc[4][4] = {};

    // per-iter: vmcnt(8) retires stage(ks) (leaves stage(ks+1) in flight);
    // single barrier; stage(ks+2); load all 16 fragments (independent
    // ds_read_b128s the compiler schedules ahead); 32 independent MFMAs.
#define ITER(ksv, bufC, bufS, WN)                                                                      \
    {                                                                                                  \
        asm volatile("s_waitcnt vmcnt(" WN ")" ::: "memory");                                          \
        __builtin_amdgcn_s_barrier();                                                                  \
        __builtin_amdgcn_sched_barrier(0);                                                             \
        if ((ksv) < 30) STAGE(bufS, (ksv) + 2);                                                        \
        v4i af[2][4], bf[2][4];                                                                        \
        _Pragma("unroll")                                                                              \
        for (int h = 0; h < 2; h++) {                                                                  \
            _Pragma("unroll")                                                                          \
            for (int mt = 0; mt < 4; mt++)                                                             \
                af[h][mt] = *(const v4i*)(As[bufC] + (((h * 2 + lh) * 256 + wr * 128 + mt * 32 + l31) << 4)); \
            _Pragma("unroll")                                                                          \
            for (int nt = 0; nt < 4; nt++)                                                             \
                bf[h][nt] = *(const v4i*)(Bs[bufC] + (((h * 2 + lh) * 256 + wc * 128 + nt * 32 + l31) << 4)); \
        }                                                                                              \
        _Pragma("unroll")                                                                              \
        for (int h = 0; h < 2; h++)                                                                    \
            _Pragma("unroll")                                                                          \
            for (int mt = 0; mt < 4; mt++)                                                             \
                _Pragma("unroll")                                                                      \
                for (int nt = 0; nt < 4; nt++)                                                         \
                    acc[mt][nt] = __builtin_amdgcn_mfma_i32_32x32x32_i8(af[h][mt], bf[h][nt], acc[mt][nt], 0, 0, 0); \
    }

    // prologue: FIFO = [stage0(8), stage1(8)]
    STAGE(0, 0);
    STAGE(1, 1);

    for (int ks = 0; ks < 30; ks += 3) {
        ITER(ks + 0, 0, 2, "8");
        ITER(ks + 1, 1, 0, "8");
        ITER(ks + 2, 2, 1, "8");
    }
    ITER(30, 0, 2, "8");  // stages nothing; vmcnt(8) retires stage(30)
    ITER(31, 1, 0, "0");  // drain: retires stage(31)

#undef ITER
#undef STAGE

    // epilogue: C/D 32x32 layout col=lane&31, row=(r&3)+8*(r>>2)+4*(lane>>5)
    float invsw = *invsw_p;
#pragma unroll
    for (int mt = 0; mt < 4; mt++) {
        int rowb = bm * 256 + wr * 128 + mt * 32 + (lh << 2);
        float sc[16];
#pragma unroll
        for (int r = 0; r < 16; r++)
            sc[r] = invsw / si[rowb + (r & 3) + ((r >> 2) << 3)];
#pragma unroll
        for (int nt = 0; nt < 4; nt++) {
            int col = bn * 256 + wc * 128 + nt * 32 + l31;
#pragma unroll
            for (int r = 0; r < 16; r++) {
                int row = rowb + (r & 3) + ((r >> 2) << 3);
                float vv = (float)acc[mt][nt][r] * sc[r];
                out[(size_t)row * N_DIM + col] = (float)(_Float16)vv;
            }
        }
    }
}

extern "C" void kernel_launch(void* const* d_in, const int* in_sizes, int n_in,
                              void* d_out, int out_size, void* d_ws, size_t ws_size,
                              hipStream_t stream) {
    const float* x = (const float*)d_in[0];
    const float* w = (const float*)d_in[1];
    float* out = (float*)d_out;
    char* ws = (char*)d_ws;

    double* part = (double*)ws;
    float* invsw = (float*)(ws + 8192);
    float* si = (float*)(ws + 12288);
    signed char* qw_t = (signed char*)(ws + 12288 + 65536);
    signed char* qx_t = qw_t + (size_t)N_DIM * K_DIM;

    void* args[] = {(void*)&x, (void*)&w, (void*)&qx_t, (void*)&qw_t,
                    (void*)&part, (void*)&si, (void*)&invsw};
    hipLaunchCooperativeKernel((void*)k_prep, dim3(512), dim3(256), args, 0, stream);
    k_gemm<<<512, 256, 0, stream>>>(qx_t, qw_t, si, invsw, out);
}

// Round 7
// 313.483 us; speedup vs baseline: 5.4623x; 1.2107x over previous
//
#include <hip/hip_runtime.h>

#define K_DIM 2048
#define N_DIM 2048
#define M_DIM 16384

typedef int v4i __attribute__((ext_vector_type(4)));
typedef int v16i __attribute__((ext_vector_type(16)));

// ---------------- ws layout ----------------
// [0]      double part[1024]     (8 KB)
// [8192]   float  invsw
// [12288]  float  si[16384]      (64 KB)
// [77824]  int8   qw_t           (4 MiB)  tiled [bn(16)][ks(32)][k16(4)][row(128)][16B]
// [+4MiB]  int8   qx_t           (32 MiB) tiled [bm(64)][ks(32)][k16(4)][row(256)][16B]

__device__ __forceinline__ void lds16(const void* g, void* l) {
    __builtin_amdgcn_global_load_lds(
        (const __attribute__((address_space(1))) unsigned int*)g,
        (__attribute__((address_space(3))) unsigned int*)l,
        16, 0, 0);
}

// ---------- kernel 1: per-block |W| partial sums (r3-verified) ----------
__global__ __launch_bounds__(256) void k_wsum(const float* __restrict__ w,
                                              double* __restrict__ part) {
    int tid = blockIdx.x * 256 + threadIdx.x;
    const float4* w4 = (const float4*)w;
    double s = 0.0;
    for (int i = tid; i < (N_DIM * K_DIM / 4); i += 262144) {
        float4 v = w4[i];
        s += (double)fabsf(v.x);
        s += (double)fabsf(v.y);
        s += (double)fabsf(v.z);
        s += (double)fabsf(v.w);
    }
#pragma unroll
    for (int off = 32; off; off >>= 1) s += __shfl_xor(s, off, 64);
    __shared__ double sp[4];
    int lane = threadIdx.x & 63, wv = threadIdx.x >> 6;
    if (lane == 0) sp[wv] = s;
    __syncthreads();
    if (threadIdx.x == 0) part[blockIdx.x] = sp[0] + sp[1] + sp[2] + sp[3];
}

// ---------- kernel 2: reduce partials + ternary-quantize W (r3-verified) ----------
__global__ __launch_bounds__(256) void k_quant_w(const float* __restrict__ w,
                                                 signed char* __restrict__ qw_t,
                                                 const double* __restrict__ part,
                                                 float* __restrict__ invsw_out) {
    double s = part[threadIdx.x] + part[threadIdx.x + 256] +
               part[threadIdx.x + 512] + part[threadIdx.x + 768];
#pragma unroll
    for (int off = 32; off; off >>= 1) s += __shfl_xor(s, off, 64);
    __shared__ double sp[4];
    __shared__ float s_invsw;
    __shared__ int lbuf[2048];  // [chunk(128)=ks*4+k16][row4(4)][b(4)]
    int lane = threadIdx.x & 63, wv = threadIdx.x >> 6;
    if (lane == 0) sp[wv] = s;
    __syncthreads();
    if (threadIdx.x == 0) {
        double total = sp[0] + sp[1] + sp[2] + sp[3];
        float mean = (float)(total * (1.0 / (double)(N_DIM * K_DIM)));
        s_invsw = fmaxf(mean, 1e-5f);
        if (blockIdx.x == 0) *invsw_out = s_invsw;
    }
    __syncthreads();
    float sw = 1.0f / s_invsw;  // reference's sw

    int row = blockIdx.x * 4 + wv;           // 0..2047
    const float4* wr_ = (const float4*)(w + (size_t)row * K_DIM);
    int k16 = (lane >> 2) & 3, b = lane & 3, ksBase = lane >> 4;
#pragma unroll
    for (int c = 0; c < 8; c++) {
        float4 v = wr_[c * 64 + lane];
        int q0 = (int)fminf(fmaxf(rintf(v.x * sw), -1.f), 1.f);
        int q1 = (int)fminf(fmaxf(rintf(v.y * sw), -1.f), 1.f);
        int q2 = (int)fminf(fmaxf(rintf(v.z * sw), -1.f), 1.f);
        int q3 = (int)fminf(fmaxf(rintf(v.w * sw), -1.f), 1.f);
        int q = (q0 & 255) | ((q1 & 255) << 8) | ((q2 & 255) << 16) | ((q3 & 255) << 24);
        int ks = 4 * c + ksBase;
        lbuf[(ks * 4 + k16) * 16 + wv * 4 + b] = q;
    }
    __syncthreads();
    // coalesced stores: 16 threads emit one 64B chunk (4 rows x 16B)
    int bn = (blockIdx.x * 4) >> 7, ri0 = (blockIdx.x * 4) & 127;
    int* qdst = (int*)(qw_t + (size_t)bn * 262144 + (size_t)ri0 * 16);
#pragma unroll
    for (int r = 0; r < 8; r++) {
        int chunk = r * 16 + (threadIdx.x >> 4);       // ks*4+k16
        int i16 = threadIdx.x & 15;                    // row4*4+b
        int ks = chunk >> 2, kk = chunk & 3;
        int row4 = i16 >> 2, bb = i16 & 3;
        qdst[ks * 2048 + kk * 512 + row4 * 4 + bb] = lbuf[chunk * 16 + i16];
    }
}

// ---------- kernel 3: per-row int8-quantize X (r3-verified) ----------
__global__ __launch_bounds__(256) void k_quant_x(const float* __restrict__ x,
                                                 signed char* __restrict__ qx_t,
                                                 float* __restrict__ si_out) {
    __shared__ int lbuf[2048];  // [chunk(128)=ks*4+k16][row4(4)][b(4)]
    int wv = threadIdx.x >> 6, lane = threadIdx.x & 63;
    int row = blockIdx.x * 4 + wv;
    const float4* xr = (const float4*)(x + (size_t)row * K_DIM);
    float4 v[8];
    float mx = 0.f;
#pragma unroll
    for (int c = 0; c < 8; c++) {
        v[c] = xr[c * 64 + lane];
        mx = fmaxf(mx, fmaxf(fmaxf(fabsf(v[c].x), fabsf(v[c].y)),
                             fmaxf(fabsf(v[c].z), fabsf(v[c].w))));
    }
#pragma unroll
    for (int off = 32; off; off >>= 1) mx = fmaxf(mx, __shfl_xor(mx, off, 64));
    float si = 127.0f / fmaxf(mx, 1e-5f);  // bit-exact vs reference
    if (lane == 0) si_out[row] = si;

    int k16 = (lane >> 2) & 3, b = lane & 3, ksBase = lane >> 4;
#pragma unroll
    for (int c = 0; c < 8; c++) {
        int q0 = (int)fminf(fmaxf(rintf(v[c].x * si), -128.f), 127.f);
        int q1 = (int)fminf(fmaxf(rintf(v[c].y * si), -128.f), 127.f);
        int q2 = (int)fminf(fmaxf(rintf(v[c].z * si), -128.f), 127.f);
        int q3 = (int)fminf(fmaxf(rintf(v[c].w * si), -128.f), 127.f);
        int q = (q0 & 255) | ((q1 & 255) << 8) | ((q2 & 255) << 16) | ((q3 & 255) << 24);
        int ks = 4 * c + ksBase;
        lbuf[(ks * 4 + k16) * 16 + wv * 4 + b] = q;
    }
    __syncthreads();
    int bm = (blockIdx.x * 4) >> 8, ri0 = (blockIdx.x * 4) & 255;
    int* qdst = (int*)(qx_t + (size_t)bm * 524288 + (size_t)ri0 * 16);
#pragma unroll
    for (int r = 0; r < 8; r++) {
        int chunk = r * 16 + (threadIdx.x >> 4);
        int i16 = threadIdx.x & 15;
        int ks = chunk >> 2, kk = chunk & 3;
        int row4 = i16 >> 2, bb = i16 & 3;
        qdst[ks * 4096 + kk * 1024 + row4 * 4 + bb] = lbuf[chunk * 16 + i16];
    }
}

// ---------- kernel 4: int8 GEMM, 256x128 block, 4 M-band waves of 64x128 ----------
// ROUND 6 CHANGE (split the traffic across both memory pipes):
//   * A-fragments: global->VGPR direct (each A byte used by exactly ONE lane —
//     LDS staging of A was pure overhead). B stays LDS-staged (128 cols shared
//     by all 4 waves).
//   * Per-CU/K-step budgets (2 blocks/CU): TA = 48 KB = 41 B/cyc (<64 ceiling),
//     LDS = 80 KB = 68 B/cyc (<90 measured ceiling) -> MFMA-bound (1170 cyc).
//     r3's all-LDS structure was 144 KB LDS = 123 B/cyc -> the measured 85 us.
//   * acc[2][4] = 128 regs + ~80 frag/addr: fits 256-reg budget at 2 waves/SIMD.
//   * Prefetch (A-regs + B-DMA for ks+1) issued right after the barrier: full
//     ~1170-cyc compute phase to land. One barrier per iter (B dbuf).
__global__ __launch_bounds__(256, 2) void k_gemm(const signed char* __restrict__ qx_t,
                                                 const signed char* __restrict__ qw_t,
                                                 const float* __restrict__ si,
                                                 const float* __restrict__ invsw_p,
                                                 float* __restrict__ out) {
    __shared__ __align__(16) signed char Bs[2][8192];   // [k16(4)][row(128)][16B]
    const int t = threadIdx.x;
    const int lane = t & 63, wv = t >> 6;      // wave = M-band wv: rows [wv*64, wv*64+64)
    const int l31 = lane & 31, lh = lane >> 5;

    // T1: bijective chunked XCD swizzle (nwg=1024, 8 XCDs, 128 blocks/XCD)
    const int wg = blockIdx.x;
    const int swz = (wg & 7) * 128 + (wg >> 3);
    const int bn = swz & 15, bm = swz >> 4;    // per XCD: 8 bm x 16 bn (qx L2-resident)

    const signed char* aT = qx_t + (size_t)bm * 524288;
    const signed char* bT = qw_t + (size_t)bn * 262144;
    const int t16 = t << 4;
    // A per-lane base: addr = ks*16384 + (2h+lh)*4096 + (wv*64 + mt*32 + l31)*16
    const signed char* aP = aT + ((size_t)lh << 12) + (((wv << 6) + l31) << 4);
    // B per-lane LDS read offset: (2h+lh)*2048 + (nt*32+l31)*16
    const int bL = (lh << 11) + (l31 << 4);

#define STAGE_B(buf, ksv)                                    \
    {                                                        \
        const signed char* bS = bT + ((size_t)(ksv) << 13);  \
        signed char* Bd = Bs[buf];                           \
        lds16(bS + t16,        Bd + t16);                    \
        lds16(bS + 4096 + t16, Bd + 4096 + t16);             \
    }

#define LOAD_A(af, ksv)                                                          \
    _Pragma("unroll") for (int h = 0; h < 2; h++)                                \
        _Pragma("unroll") for (int mt = 0; mt < 2; mt++)                         \
            af[h][mt] = *(const v4i*)(aP + ((size_t)(ksv) << 14) + (h << 13) + (mt << 9));

    v16i acc[2][4] = {};

    // per-iter: vmcnt(0)+barrier (B(ks) DMA complete; B(ks-1) readers done);
    // prefetch A(ks+1)->regs + B(ks+1)->other buf; ds_read B frags; 16 MFMA.
#define ITER(ksv, afC, afN, bufC)                                                                     \
    {                                                                                                 \
        asm volatile("s_waitcnt vmcnt(0)" ::: "memory");                                              \
        __builtin_amdgcn_s_barrier();                                                                 \
        __builtin_amdgcn_sched_barrier(0);                                                            \
        if ((ksv) < 31) {                                                                             \
            LOAD_A(afN, (ksv) + 1);                                                                   \
            STAGE_B((bufC) ^ 1, (ksv) + 1);                                                           \
        }                                                                                             \
        _Pragma("unroll")                                                                             \
        for (int h = 0; h < 2; h++) {                                                                 \
            v4i bf[4];                                                                                \
            _Pragma("unroll")                                                                         \
            for (int nt = 0; nt < 4; nt++)                                                            \
                bf[nt] = *(const v4i*)(Bs[bufC] + bL + (h << 12) + (nt << 9));                        \
            __builtin_amdgcn_s_setprio(1);                                                            \
            _Pragma("unroll")                                                                         \
            for (int mt = 0; mt < 2; mt++)                                                            \
                _Pragma("unroll")                                                                     \
                for (int nt = 0; nt < 4; nt++)                                                        \
                    acc[mt][nt] = __builtin_amdgcn_mfma_i32_32x32x32_i8(afC[h][mt], bf[nt], acc[mt][nt], 0, 0, 0); \
            __builtin_amdgcn_s_setprio(0);                                                            \
        }                                                                                             \
    }

    v4i afA[2][2], afB[2][2];
    // prologue
    LOAD_A(afA, 0);
    STAGE_B(0, 0);

    for (int ks = 0; ks < 32; ks += 2) {
        ITER(ks,     afA, afB, 0);
        ITER(ks + 1, afB, afA, 1);
    }

#undef ITER
#undef LOAD_A
#undef STAGE_B

    // epilogue: C/D 32x32 layout col=lane&31, row=(r&3)+8*(r>>2)+4*(lane>>5)
    float invsw = *invsw_p;
#pragma unroll
    for (int mt = 0; mt < 2; mt++) {
        int rowb = bm * 256 + wv * 64 + mt * 32 + (lh << 2);
        float sc[16];
#pragma unroll
        for (int r = 0; r < 16; r++)
            sc[r] = invsw / si[rowb + (r & 3) + ((r >> 2) << 3)];
#pragma unroll
        for (int nt = 0; nt < 4; nt++) {
            int col = bn * 128 + nt * 32 + l31;
#pragma unroll
            for (int r = 0; r < 16; r++) {
                int row = rowb + (r & 3) + ((r >> 2) << 3);
                float vv = (float)acc[mt][nt][r] * sc[r];
                out[(size_t)row * N_DIM + col] = (float)(_Float16)vv;
            }
        }
    }
}

extern "C" void kernel_launch(void* const* d_in, const int* in_sizes, int n_in,
                              void* d_out, int out_size, void* d_ws, size_t ws_size,
                              hipStream_t stream) {
    const float* x = (const float*)d_in[0];
    const float* w = (const float*)d_in[1];
    float* out = (float*)d_out;
    char* ws = (char*)d_ws;

    double* part = (double*)ws;
    float* invsw = (float*)(ws + 8192);
    float* si = (float*)(ws + 12288);
    signed char* qw_t = (signed char*)(ws + 12288 + 65536);
    signed char* qx_t = qw_t + (size_t)N_DIM * K_DIM;

    k_wsum<<<1024, 256, 0, stream>>>(w, part);
    k_quant_x<<<4096, 256, 0, stream>>>(x, qx_t, si);
    k_quant_w<<<512, 256, 0, stream>>>(w, qw_t, part, invsw);
    k_gemm<<<1024, 256, 0, stream>>>(qx_t, qw_t, si, invsw, out);
}